// Round 12
// baseline (295.042 us; speedup 1.0000x reference)
//
#include <hip/hip_runtime.h>

#define T_LEN 65536
#define C_CH 8
#define CLEN 16
#define NB 16
#define WIN (CLEN * NB)          // 256 steps per window
#define NBLK 512                 // 8 whi x 8 ch x 8 slot; 4 waves/block, 1 window/wave
#define SCANW 6                  // 384 bits scanned per window
#define MAXB 32                  // step-block size
#define NWAVE 4

typedef short bf16x8 __attribute__((ext_vector_type(8)));
typedef float f32x4 __attribute__((ext_vector_type(4)));
typedef unsigned int uint;
typedef unsigned long long u64;

#define MFMA32 __builtin_amdgcn_mfma_f32_16x16x32_bf16

#define SC_RZ 1.4426950408889634f   // log2(e): folded into r/z rows
#define SC_N  2.8853900817779268f   // 2*log2(e): folded into n rows

__device__ __forceinline__ uint f2bf(float f) {           // RNE float->bf16
    uint u = __float_as_uint(f);
    return (u + 0x7FFFu + ((u >> 16) & 1u)) >> 16;
}
__device__ __forceinline__ uint pk(float a, float b) {
    return f2bf(a) | (f2bf(b) << 16);
}
__device__ __forceinline__ uint cvtpk(float lo, float hi) {
    uint r;
    asm("v_cvt_pk_bf16_f32 %0, %1, %2" : "=v"(r) : "v"(lo), "v"(hi));
    return r;
}
// builtin exp2: compiler knows TRANS hazard (inline-asm version was R7's bug)
__device__ __forceinline__ float expneg(float x) { return __builtin_amdgcn_exp2f(-x); }
__device__ __forceinline__ bf16x8 mk8(uint a, uint b, uint c, uint d) {
    union { uint u[4]; bf16x8 v; } x;
    x.u[0] = a; x.u[1] = b; x.u[2] = c; x.u[3] = d;
    return x.v;
}
__device__ __forceinline__ float rcpf(float v) { return __builtin_amdgcn_rcpf(v); }
// volatile LDS reads: defeat LICM (would re-hoist weights into registers)
__device__ __forceinline__ uint  vldu(const uint* p)  { return *(const volatile uint*)p; }
__device__ __forceinline__ float vldf(const float* p) { return *(const volatile float*)p; }

// (256,1): NO register cap (caps caused every spill: R4/R8/R11). 4 waves share
// one LDS weight copy -> per-wave arch demand ~130 + ~32 AGPR fits 2 waves/SIMD
// naturally. 512 blocks x 57KB LDS = 2 blocks/CU = 8 waves/CU, all resident.
__global__ __launch_bounds__(256, 1) void gru_mfma(
    const float* __restrict__ x,     // (T,10,8)
    const int*   __restrict__ cg,    // (T,8)
    const int*   __restrict__ cs,    // (T,8)
    const float* __restrict__ W_ih,  // (8,192,4)
    const float* __restrict__ W_hh,  // (8,192,64)
    const float* __restrict__ b_ih,  // (8,192)
    const float* __restrict__ b_hh,  // (8,192)
    const float* __restrict__ W_out, // (8,1,64)
    const float* __restrict__ b_out, // (8,)
    float* __restrict__ y)           // (T,)
{
    // A-fragments as dword PLANES: read addr = lane*4 -> 2 lanes/bank = free
    __shared__ uint   AhP[4][24][64];   // W_hh frags: [dword][tile*2+kt][lane]
    __shared__ uint   AxP[2][12][64];   // W_ih/bias frags: [dword][tile][lane]
    __shared__ float4 bhnL[4][4];       // [tn][l4] n-gate b_hh C-init (broadcast)
    __shared__ float4 wofL[4][4];       // [tm][l4] W_out slice (broadcast)
    __shared__ u64    stw[NWAVE][SCANW], acw[NWAVE][SCANW];
    __shared__ int    sb[NWAVE][NB + 1];
    __shared__ float  yw[NWAVE][NB][MAXB + 1];
    __shared__ uint2  bxl[NWAVE][MAXB][NB];

    const int tid = threadIdx.x;
    const int wv = tid >> 6, lane = tid & 63;
    const int l15 = lane & 15, l4 = lane >> 4;
    // decode: bid%8 = slot keeps channels of one time-range on one XCD;
    // block handles 4 consecutive windows (one per wave) of ONE channel.
    const int slot = blockIdx.x & 7;
    const int c    = (blockIdx.x >> 3) & 7;
    const int whi  = blockIdx.x >> 6;            // 0..7
    const int w    = (whi * 8 + slot) * 4 + wv;  // 0..255
    const int RB   = w * WIN;

    // ---- per-wave scan of cs/cg bits (wave-private LDS, no barrier needed) ----
    for (int rr = 0; rr < SCANW; ++rr) {
        int t = RB + rr * 64 + lane;
        int sv = 0, av = 0;
        if (t < T_LEN) { sv = cs[t * C_CH + c]; av = cg[t * C_CH + c]; }
        u64 m1 = __ballot(sv == 1);
        u64 m2 = __ballot(av == 1);
        if (lane == 0) { stw[wv][rr] = m1; acw[wv][rr] = m2; }
    }

    // ---- 17 start-aligned boundaries: sb[k] = first start >= RB + k*CLEN ----
    if (lane <= NB) {
        int rel = lane * CLEN;
        int q = rel >> 6, r0 = rel & 63;
        u64 m = stw[wv][q] >> r0;
        int pos = -1;
        if (m) pos = rel + __ffsll(m) - 1;
        else {
            for (int q2 = q + 1; q2 < SCANW; ++q2)
                if (stw[wv][q2]) { pos = (q2 << 6) + __ffsll(stw[wv][q2]) - 1; break; }
        }
        int Sa;
        if (pos >= 0) Sa = RB + pos;
        else {  // ultra-rare fallback: serial scan past region
            int t = RB + SCANW * 64;
            while (t < T_LEN && cs[t * C_CH + c] != 1) ++t;
            Sa = t;
        }
        sb[wv][lane] = min(Sa, T_LEN);
    }

    // ---- cooperative weight staging (shared across the 4 waves) ----
    // wave wv stages tile-slots tk = 6*wv .. 6*wv+5  (tk = tm*2 + kt)
    for (int tk = 6 * wv; tk < 6 * wv + 6; ++tk) {
        int tm = tk >> 1, kt = tk & 1;
        const float sc = (tm < 8) ? SC_RZ : SC_N;
        const float* p = W_hh + c * 192 * 64 + (16 * tm + l15) * 64 + 32 * kt + 4 * l4;
        float4 a = *(const float4*)p;
        float4 b = *(const float4*)(p + 16);
        AhP[0][tk][lane] = pk(a.x * sc, a.y * sc);
        AhP[1][tk][lane] = pk(a.z * sc, a.w * sc);
        AhP[2][tk][lane] = pk(b.x * sc, b.y * sc);
        AhP[3][tk][lane] = pk(b.z * sc, b.w * sc);
    }
    if (wv == 0) {
        // W_ih cols (k=0..3, l4==0) + ones-column bias at k=4 (l4==1):
        // r/z tiles: (b_ih+b_hh)*log2e merged; n tiles: b_ih*2log2e (gx acc)
#pragma unroll
        for (int tm = 0; tm < 12; ++tm) {
            const float sc = (tm < 8) ? SC_RZ : SC_N;
            int row = 16 * tm + l15;
            uint d0 = 0, d1 = 0;
            if (l4 == 0) {
                float4 wi4 = *(const float4*)(W_ih + (c * 192 + row) * 4);
                d0 = pk(wi4.x * sc, wi4.y * sc);
                d1 = pk(wi4.z * sc, wi4.w * sc);
            } else if (l4 == 1) {
                float bias = (tm < 8) ? (b_ih[c * 192 + row] + b_hh[c * 192 + row]) * SC_RZ
                                      : b_ih[c * 192 + row] * SC_N;
                d0 = f2bf(bias);
            }
            AxP[0][tm][lane] = d0;
            AxP[1][tm][lane] = d1;
        }
    } else if (wv == 1 && lane < 16) {
        int tn = lane >> 2, q = lane & 3;
        float4 v = *(const float4*)(b_hh + c * 192 + 128 + 16 * tn + 4 * q);
        bhnL[tn][q] = make_float4(v.x * SC_N, v.y * SC_N, v.z * SC_N, v.w * SC_N);
        wofL[tn][q] = *(const float4*)(W_out + c * 64 + 16 * tn + 4 * q);
    }
    __syncthreads();   // the ONLY block-wide barrier (waves diverge after this)

    const int S = sb[wv][l15];
    const int len = sb[wv][l15 + 1] - S;
    int Lmax = len;
#pragma unroll
    for (int o = 1; o < 16; o <<= 1) Lmax = max(Lmax, __shfl_xor(Lmax, o));

    const float bo = b_out[c];

    // ---- state: h fp32 (D-layout) + bf16 B-frags (same lane mapping) ----
    float h[16];
    uint B0[4], B1[4];
#pragma unroll
    for (int i = 0; i < 16; ++i) h[i] = 0.f;
#pragma unroll
    for (int i = 0; i < 4; ++i) { B0[i] = 0u; B1[i] = 0u; }
    const uint bx_c0 = (l4 == 1) ? 0x00003F80u : 0u;  // bf16(1.0) at k=4
    const f32x4 z4 = {0.f, 0.f, 0.f, 0.f};

    for (int s0 = 0; s0 < Lmax; s0 += MAXB) {
        const int Lb = min(MAXB, Lmax - s0);

        // stage Bx payloads (wave-private; p&15 == l15 at stride 64)
        const int npair = Lb * NB;
        for (int p = lane; p < npair; p += 64) {
            int s = p >> 4;
            int t = min(S + s0 + s, T_LEN - 1);
            const float* xp = x + (size_t)t * 80 + 8 + c;
            bxl[wv][s][l15] = make_uint2(pk(xp[0], xp[8]), pk(xp[16], xp[24]));
        }
        // per-lane reset mask for its column, this step-block
        int off = (S - RB) + s0;
        int q = off >> 6, r0 = off & 63;
        u64 w0s = (q < SCANW) ? stw[wv][q] : 0ull;
        u64 w1s = (q + 1 < SCANW) ? stw[wv][q + 1] : 0ull;
        u64 ms = (w0s >> r0) | (r0 ? (w1s << (64 - r0)) : 0ull);
        // no barrier: within-wave ds ordering is compiler-managed (lgkmcnt)

        for (int s = 0; s < Lb; ++s) {
            const bool rst = (ms >> s) & 1;
#pragma unroll
            for (int i = 0; i < 16; ++i) h[i] = rst ? 0.f : h[i];
#pragma unroll
            for (int i = 0; i < 4; ++i) {
                B0[i] = rst ? 0u : B0[i];
                B1[i] = rst ? 0u : B1[i];
            }

            uint2 bx = bxl[wv][s][l15];
            const bf16x8 Bx  = mk8((lane < 16) ? bx.x : bx_c0,
                                   (lane < 16) ? bx.y : 0u, 0u, 0u);
            const bf16x8 Bh0 = mk8(B0[0], B0[1], B0[2], B0[3]);
            const bf16x8 Bh1 = mk8(B1[0], B1[1], B1[2], B1[3]);

            float yp = 0.f;
            uint nB[8];
#pragma unroll
            for (int tm = 0; tm < 4; ++tm) {
                const int tz = tm + 4, tn = tm + 8;
                // volatile plane reads: conflict-free, per-step (no LICM hoist)
                bf16x8 Ar0 = mk8(vldu(&AhP[0][2*tm  ][lane]), vldu(&AhP[1][2*tm  ][lane]),
                                 vldu(&AhP[2][2*tm  ][lane]), vldu(&AhP[3][2*tm  ][lane]));
                bf16x8 Ar1 = mk8(vldu(&AhP[0][2*tm+1][lane]), vldu(&AhP[1][2*tm+1][lane]),
                                 vldu(&AhP[2][2*tm+1][lane]), vldu(&AhP[3][2*tm+1][lane]));
                bf16x8 Az0 = mk8(vldu(&AhP[0][2*tz  ][lane]), vldu(&AhP[1][2*tz  ][lane]),
                                 vldu(&AhP[2][2*tz  ][lane]), vldu(&AhP[3][2*tz  ][lane]));
                bf16x8 Az1 = mk8(vldu(&AhP[0][2*tz+1][lane]), vldu(&AhP[1][2*tz+1][lane]),
                                 vldu(&AhP[2][2*tz+1][lane]), vldu(&AhP[3][2*tz+1][lane]));
                bf16x8 An0 = mk8(vldu(&AhP[0][2*tn  ][lane]), vldu(&AhP[1][2*tn  ][lane]),
                                 vldu(&AhP[2][2*tn  ][lane]), vldu(&AhP[3][2*tn  ][lane]));
                bf16x8 An1 = mk8(vldu(&AhP[0][2*tn+1][lane]), vldu(&AhP[1][2*tn+1][lane]),
                                 vldu(&AhP[2][2*tn+1][lane]), vldu(&AhP[3][2*tn+1][lane]));
                uint axr0 = vldu(&AxP[0][tm][lane]), axr1 = vldu(&AxP[1][tm][lane]);
                uint axz0 = vldu(&AxP[0][tz][lane]), axz1 = vldu(&AxP[1][tz][lane]);
                uint axn0 = vldu(&AxP[0][tn][lane]), axn1 = vldu(&AxP[1][tn][lane]);
                f32x4 ci;
                ci[0] = vldf(&bhnL[tm][l4].x); ci[1] = vldf(&bhnL[tm][l4].y);
                ci[2] = vldf(&bhnL[tm][l4].z); ci[3] = vldf(&bhnL[tm][l4].w);

                f32x4 ar = MFMA32(mk8(axr0, axr1, 0u, 0u), Bx, z4, 0, 0, 0);
                ar = MFMA32(Ar0, Bh0, ar, 0, 0, 0);
                ar = MFMA32(Ar1, Bh1, ar, 0, 0, 0);
                f32x4 az = MFMA32(mk8(axz0, axz1, 0u, 0u), Bx, z4, 0, 0, 0);
                az = MFMA32(Az0, Bh0, az, 0, 0, 0);
                az = MFMA32(Az1, Bh1, az, 0, 0, 0);
                f32x4 gx = MFMA32(mk8(axn0, axn1, 0u, 0u), Bx, z4, 0, 0, 0);
                f32x4 gh = MFMA32(An0, Bh0, ci, 0, 0, 0);
                gh = MFMA32(An1, Bh1, gh, 0, 0, 0);

                float wv0 = vldf(&wofL[tm][l4].x), wv1 = vldf(&wofL[tm][l4].y);
                float wv2 = vldf(&wofL[tm][l4].z), wv3 = vldf(&wofL[tm][l4].w);

                float hv[4];
#pragma unroll
                for (int i = 0; i < 4; ++i) {
                    // pre-activations pre-scaled by log2e (r/z) / 2log2e (n)
                    float rr = rcpf(1.f + expneg(ar[i]));
                    float zz = rcpf(1.f + expneg(az[i]));
                    float np2 = fmaf(rr, gh[i], gx[i]);
                    float nn = fmaf(2.f, rcpf(1.f + expneg(np2)), -1.f);
                    float hh = fmaf(zz, h[4 * tm + i] - nn, nn);
                    h[4 * tm + i] = hh;
                    hv[i] = hh;
                    float wvv = (i == 0) ? wv0 : (i == 1) ? wv1 : (i == 2) ? wv2 : wv3;
                    yp = fmaf(wvv, hh, yp);
                }
                nB[2 * tm]     = cvtpk(hv[0], hv[1]);
                nB[2 * tm + 1] = cvtpk(hv[2], hv[3]);
            }
            // D-layout == B-layout: tiles 0,1 -> Bh0; 2,3 -> Bh1
            B0[0] = nB[0]; B0[1] = nB[1]; B0[2] = nB[2]; B0[3] = nB[3];
            B1[0] = nB[4]; B1[1] = nB[5]; B1[2] = nB[6]; B1[3] = nB[7];

            float t1 = yp + __shfl_xor(yp, 16);
            float t2 = t1 + __shfl_xor(t1, 32);
            if (lane < 16 && (s0 + s) < len) yw[wv][lane][s] = t2;
        }

        // write back (wave-private): one coalesced atomic row per chunk
        for (int b = 0; b < NB; ++b) {
            int Sb = sb[wv][b];
            int lenb = sb[wv][b + 1] - Sb;
            int sg = s0 + lane;
            if (lane < Lb && sg < lenb) {
                int offa = (Sb - RB) + sg;
                int qa = offa >> 6;
                bool act;
                if (qa < SCANW) act = (acw[wv][qa] >> (offa & 63)) & 1;
                else            act = cg[(Sb + sg) * C_CH + c] == 1;  // rare
                if (act) atomicAdd(&y[Sb + sg], yw[wv][b][lane] + bo);
            }
        }
    }
}

extern "C" void kernel_launch(void* const* d_in, const int* in_sizes, int n_in,
                              void* d_out, int out_size, void* d_ws, size_t ws_size,
                              hipStream_t stream) {
    const float* x     = (const float*)d_in[0];
    const int*   cg    = (const int*)  d_in[1];
    const int*   cs    = (const int*)  d_in[2];
    const float* W_ih  = (const float*)d_in[3];
    const float* W_hh  = (const float*)d_in[4];
    const float* b_ih  = (const float*)d_in[5];
    const float* b_hh  = (const float*)d_in[6];
    const float* W_out = (const float*)d_in[7];
    const float* b_out = (const float*)d_in[8];
    float* y = (float*)d_out;

    hipMemsetAsync(y, 0, (size_t)out_size * sizeof(float), stream);
    gru_mfma<<<NBLK, 256, 0, stream>>>(x, cg, cs, W_ih, W_hh, b_ih, b_hh,
                                       W_out, b_out, y);
}

// Round 13
// 81.420 us; speedup vs baseline: 3.6237x; 3.6237x over previous
//
#include <hip/hip_runtime.h>

#define T_LEN 65536
#define C_CH 8
#define CLEN 16
#define NB 16
#define WIN (CLEN * NB)          // 256 steps per window
#define NBLK 2048                // 32 whi x 8 ch x 8 slot; 1 window per wave
#define SCANW 6                  // 384 bits scanned per window
#define MAXB 32                  // step-block size

typedef short bf16x8 __attribute__((ext_vector_type(8)));
typedef float f32x4 __attribute__((ext_vector_type(4)));
typedef unsigned int uint;
typedef uint u32x4 __attribute__((ext_vector_type(4)));
typedef unsigned long long u64;

#define MFMA32 __builtin_amdgcn_mfma_f32_16x16x32_bf16

#define SC_RZ 1.4426950408889634f   // log2(e): folded into r/z rows
#define SC_N  2.8853900817779268f   // 2*log2(e): folded into n rows

__device__ __forceinline__ uint f2bf(float f) {           // RNE float->bf16
    uint u = __float_as_uint(f);
    return (u + 0x7FFFu + ((u >> 16) & 1u)) >> 16;
}
__device__ __forceinline__ uint pk(float a, float b) {
    return f2bf(a) | (f2bf(b) << 16);
}
__device__ __forceinline__ uint cvtpk(float lo, float hi) {
    uint r;
    asm("v_cvt_pk_bf16_f32 %0, %1, %2" : "=v"(r) : "v"(lo), "v"(hi));
    return r;
}
// builtin exp2: compiler knows TRANS hazard (inline-asm version was R7's bug)
__device__ __forceinline__ float expneg(float x) { return __builtin_amdgcn_exp2f(-x); }
__device__ __forceinline__ bf16x8 mk8(uint a, uint b, uint c, uint d) {
    union { uint u[4]; bf16x8 v; } x;
    x.u[0] = a; x.u[1] = b; x.u[2] = c; x.u[3] = d;
    return x.v;
}
__device__ __forceinline__ bf16x8 q2b(u32x4 q) {
    union { u32x4 q; bf16x8 b; } u; u.q = q; return u.b;
}
__device__ __forceinline__ float rcpf(float v) { return __builtin_amdgcn_rcpf(v); }

// (64,2) + AGPR pinning: the 26 A-fragment quads (W_hh + W_out) are forced
// into the AGPR half of the unified file ("a" constraint); MFMA reads A/B
// from AGPR directly (ISA: "A,B from VGPR or AGPR"). Arch demand drops to
// ~110 <= 128 -> 2 clean waves/SIMD (R8-R12: reported VGPR<=128 <=> 19% occ).
__global__ __launch_bounds__(64, 2) void gru_mfma(
    const float* __restrict__ x,     // (T,10,8)
    const int*   __restrict__ cg,    // (T,8)
    const int*   __restrict__ cs,    // (T,8)
    const float* __restrict__ W_ih,  // (8,192,4)
    const float* __restrict__ W_hh,  // (8,192,64)
    const float* __restrict__ b_ih,  // (8,192)
    const float* __restrict__ b_hh,  // (8,192)
    const float* __restrict__ W_out, // (8,1,64)
    const float* __restrict__ b_out, // (8,)
    float* __restrict__ y)           // (T,)
{
    __shared__ u64 stw[SCANW], acw[SCANW];
    __shared__ int sb[NB + 1];
    __shared__ float yw[NB][MAXB + 1];
    __shared__ uint2 bxl[MAXB][NB];

    const int lane = threadIdx.x;
    const int l15 = lane & 15, l4 = lane >> 4;
    // decode: all 8 channels of one time-slot share an XCD (bid%8 = w%8)
    const int slot = blockIdx.x & 7;
    const int c    = (blockIdx.x >> 3) & 7;
    const int whi  = blockIdx.x >> 6;        // 0..31
    const int w    = whi * 8 + slot;         // window id 0..255
    const int RB   = w * WIN;

    // ---- cooperative scan of cs/cg bits ----
    for (int rr = 0; rr < SCANW; ++rr) {
        int t = RB + rr * 64 + lane;
        int sv = 0, av = 0;
        if (t < T_LEN) { sv = cs[t * C_CH + c]; av = cg[t * C_CH + c]; }
        u64 m1 = __ballot(sv == 1);
        u64 m2 = __ballot(av == 1);
        if (lane == 0) { stw[rr] = m1; acw[rr] = m2; }
    }
    __syncthreads();

    // ---- 17 start-aligned boundaries: sb[k] = first start >= RB + k*CLEN ----
    if (lane <= NB) {
        int rel = lane * CLEN;
        int q = rel >> 6, r0 = rel & 63;
        u64 m = stw[q] >> r0;
        int pos = -1;
        if (m) pos = rel + __ffsll(m) - 1;
        else {
            for (int q2 = q + 1; q2 < SCANW; ++q2)
                if (stw[q2]) { pos = (q2 << 6) + __ffsll(stw[q2]) - 1; break; }
        }
        int Sa;
        if (pos >= 0) Sa = RB + pos;
        else {  // ultra-rare fallback: serial scan past region
            int t = RB + SCANW * 64;
            while (t < T_LEN && cs[t * C_CH + c] != 1) ++t;
            Sa = t;
        }
        sb[lane] = min(Sa, T_LEN);
    }
    __syncthreads();

    const int S = sb[l15];
    const int len = sb[l15 + 1] - S;
    int Lmax = len;
#pragma unroll
    for (int o = 1; o < 16; o <<= 1) Lmax = max(Lmax, __shfl_xor(Lmax, o));

    // ---- A-fragments -> AGPRs (window constants), log2e pre-scaled ----
    const float* Wc = W_hh + c * 192 * 64;
    u32x4 AhA[12][2];
#pragma unroll
    for (int tm = 0; tm < 12; ++tm) {
        const float sc = (tm < 8) ? SC_RZ : SC_N;
#pragma unroll
        for (int kt = 0; kt < 2; ++kt) {
            const float* p = Wc + (16 * tm + l15) * 64 + 32 * kt + 4 * l4;
            float4 a = *(const float4*)p;
            float4 b = *(const float4*)(p + 16);
            AhA[tm][kt] = (u32x4){ pk(a.x * sc, a.y * sc), pk(a.z * sc, a.w * sc),
                                   pk(b.x * sc, b.y * sc), pk(b.z * sc, b.w * sc) };
            asm volatile("" : "+a"(AhA[tm][kt]));   // pin quad into AGPRs
        }
    }
    // W_out as a 13th A-tile (row 0 only): y_t = W_out . h_t via 2 MFMAs
    u32x4 WoA[2];
#pragma unroll
    for (int kt = 0; kt < 2; ++kt) {
        uint d0 = 0, d1 = 0, d2 = 0, d3 = 0;
        if (l15 == 0) {
            const float* wp = W_out + c * 64 + 32 * kt + 4 * l4;
            d0 = pk(wp[0], wp[1]);  d1 = pk(wp[2], wp[3]);
            d2 = pk(wp[16], wp[17]); d3 = pk(wp[18], wp[19]);
        }
        WoA[kt] = (u32x4){ d0, d1, d2, d3 };
        asm volatile("" : "+a"(WoA[kt]));
    }

    // W_ih cols (k=0..3) + ones-column bias at k=4: r/z merged b_ih+b_hh; n: b_ih
    uint Axd[12][2];
#pragma unroll
    for (int tm = 0; tm < 12; ++tm) {
        const float sc = (tm < 8) ? SC_RZ : SC_N;
        int row = 16 * tm + l15;
        uint d0 = 0, d1 = 0;
        if (l4 == 0) {
            float4 wi4 = *(const float4*)(W_ih + (c * 192 + row) * 4);
            d0 = pk(wi4.x * sc, wi4.y * sc);
            d1 = pk(wi4.z * sc, wi4.w * sc);
        } else if (l4 == 1) {
            float bias = (tm < 8) ? (b_ih[c * 192 + row] + b_hh[c * 192 + row]) * SC_RZ
                                  : b_ih[c * 192 + row] * SC_N;
            d0 = f2bf(bias);
        }
        Axd[tm][0] = d0; Axd[tm][1] = d1;
    }
    // n-gate b_hh as fp32 C-init (row = 4*l4+i, column-independent)
    f32x4 bhn4[4];
#pragma unroll
    for (int tn = 0; tn < 4; ++tn) {
        float4 v = *(const float4*)(b_hh + c * 192 + 128 + 16 * tn + 4 * l4);
        bhn4[tn] = (f32x4){v.x * SC_N, v.y * SC_N, v.z * SC_N, v.w * SC_N};
    }
    const float bo = b_out[c];

    // ---- state: bf16 B-frags ONLY (h_old re-expanded by shift; no fp32 h) ----
    uint B0[4], B1[4];
#pragma unroll
    for (int i = 0; i < 4; ++i) { B0[i] = 0u; B1[i] = 0u; }
    const uint bx_c0 = (l4 == 1) ? 0x00003F80u : 0u;  // bf16(1.0) at k=4
    const f32x4 z4 = {0.f, 0.f, 0.f, 0.f};

    for (int s0 = 0; s0 < Lmax; s0 += MAXB) {
        const int Lb = min(MAXB, Lmax - s0);

        // stage Bx payloads: bxl[s][b] = packed bf16 {x1..x4}(t = S_b+s0+s)
        const int npair = Lb * NB;
        for (int p = lane; p < npair; p += 64) {
            int s = p >> 4;
            int t = min(sb[p & 15] + s0 + s, T_LEN - 1);
            const float* xp = x + (size_t)t * 80 + 8 + c;
            bxl[s][p & 15] = make_uint2(pk(xp[0], xp[8]), pk(xp[16], xp[24]));
        }
        // per-lane reset mask for its column, this step-block
        int off = (S - RB) + s0;
        int q = off >> 6, r0 = off & 63;
        u64 w0s = (q < SCANW) ? stw[q] : 0ull;
        u64 w1s = (q + 1 < SCANW) ? stw[q + 1] : 0ull;
        u64 ms = (w0s >> r0) | (r0 ? (w1s << (64 - r0)) : 0ull);
        __syncthreads();

        for (int s = 0; s < Lb; ++s) {
            const bool rst = (ms >> s) & 1;
#pragma unroll
            for (int i = 0; i < 4; ++i) {
                B0[i] = rst ? 0u : B0[i];
                B1[i] = rst ? 0u : B1[i];
            }

            uint2 bx = bxl[s][l15];
            const bf16x8 Bx  = mk8((lane < 16) ? bx.x : bx_c0,
                                   (lane < 16) ? bx.y : 0u, 0u, 0u);
            const bf16x8 Bh0 = mk8(B0[0], B0[1], B0[2], B0[3]);
            const bf16x8 Bh1 = mk8(B1[0], B1[1], B1[2], B1[3]);

            uint nB[8];
#pragma unroll
            for (int tm = 0; tm < 4; ++tm) {
                const int tz = tm + 4, tn = tm + 8;
                f32x4 ar = MFMA32(mk8(Axd[tm][0], Axd[tm][1], 0u, 0u), Bx, z4, 0, 0, 0);
                ar = MFMA32(q2b(AhA[tm][0]), Bh0, ar, 0, 0, 0);
                ar = MFMA32(q2b(AhA[tm][1]), Bh1, ar, 0, 0, 0);
                f32x4 az = MFMA32(mk8(Axd[tz][0], Axd[tz][1], 0u, 0u), Bx, z4, 0, 0, 0);
                az = MFMA32(q2b(AhA[tz][0]), Bh0, az, 0, 0, 0);
                az = MFMA32(q2b(AhA[tz][1]), Bh1, az, 0, 0, 0);
                f32x4 gx = MFMA32(mk8(Axd[tn][0], Axd[tn][1], 0u, 0u), Bx, z4, 0, 0, 0);
                f32x4 gh = MFMA32(q2b(AhA[tn][0]), Bh0, bhn4[tm], 0, 0, 0);
                gh = MFMA32(q2b(AhA[tn][1]), Bh1, gh, 0, 0, 0);

                float hv[4];
#pragma unroll
                for (int i = 0; i < 4; ++i) {
                    // pre-activations pre-scaled by log2e (r/z) / 2log2e (n)
                    float rr = rcpf(1.f + expneg(ar[i]));
                    float zz = rcpf(1.f + expneg(az[i]));
                    float np2 = fmaf(rr, gh[i], gx[i]);
                    float nn = fmaf(2.f, rcpf(1.f + expneg(np2)), -1.f);
                    // h_old from the bf16 state frag (1-op expand)
                    const uint bd = (tm < 2) ? B0[2 * (tm & 1) + (i >> 1)]
                                             : B1[2 * (tm & 1) + (i >> 1)];
                    const float hold = __uint_as_float((i & 1) ? (bd & 0xFFFF0000u)
                                                               : (bd << 16));
                    float hh = fmaf(zz, hold - nn, nn);
                    hv[i] = hh;
                }
                nB[2 * tm]     = cvtpk(hv[0], hv[1]);
                nB[2 * tm + 1] = cvtpk(hv[2], hv[3]);
            }
            // D-layout == B-layout: tiles 0,1 -> Bh0; 2,3 -> Bh1
            B0[0] = nB[0]; B0[1] = nB[1]; B0[2] = nB[2]; B0[3] = nB[3];
            B1[0] = nB[4]; B1[1] = nB[5]; B1[2] = nB[6]; B1[3] = nB[7];

            // y_t = W_out . h_t via the 13th tile (row 0 -> lanes 0-15, reg 0)
            const bf16x8 Bh0n = mk8(B0[0], B0[1], B0[2], B0[3]);
            const bf16x8 Bh1n = mk8(B1[0], B1[1], B1[2], B1[3]);
            f32x4 y4 = MFMA32(q2b(WoA[0]), Bh0n, z4, 0, 0, 0);
            y4 = MFMA32(q2b(WoA[1]), Bh1n, y4, 0, 0, 0);
            if (lane < 16 && (s0 + s) < len) yw[lane][s] = y4[0];
        }
        __syncthreads();

        // write back: one coalesced atomic row per chunk (channels collide)
        for (int b = 0; b < NB; ++b) {
            int Sb = sb[b];
            int lenb = sb[b + 1] - Sb;
            int sg = s0 + lane;
            if (lane < Lb && sg < lenb) {
                int offa = (Sb - RB) + sg;
                int qa = offa >> 6;
                bool act;
                if (qa < SCANW) act = (acw[qa] >> (offa & 63)) & 1;
                else            act = cg[(Sb + sg) * C_CH + c] == 1;  // rare
                if (act) atomicAdd(&y[Sb + sg], yw[b][lane] + bo);
            }
        }
        __syncthreads();
    }
}

extern "C" void kernel_launch(void* const* d_in, const int* in_sizes, int n_in,
                              void* d_out, int out_size, void* d_ws, size_t ws_size,
                              hipStream_t stream) {
    const float* x     = (const float*)d_in[0];
    const int*   cg    = (const int*)  d_in[1];
    const int*   cs    = (const int*)  d_in[2];
    const float* W_ih  = (const float*)d_in[3];
    const float* W_hh  = (const float*)d_in[4];
    const float* b_ih  = (const float*)d_in[5];
    const float* b_hh  = (const float*)d_in[6];
    const float* W_out = (const float*)d_in[7];
    const float* b_out = (const float*)d_in[8];
    float* y = (float*)d_out;

    hipMemsetAsync(y, 0, (size_t)out_size * sizeof(float), stream);
    gru_mfma<<<NBLK, 64, 0, stream>>>(x, cg, cs, W_ih, W_hh, b_ih, b_hh,
                                      W_out, b_out, y);
}